// Round 4
// baseline (310.904 us; speedup 1.0000x reference)
//
#include <hip/hip_runtime.h>

// PFNLayer feature augmentation (PointPillars), MI355X.
// One 32-lane half-wave per pillar; lane = point slot.
// Layout: d_out = [coors_as_float (P*4)] ++ [features (P*9*32)].
//
// Reference semantics replicated exactly:
//  - mean = sum over ALL 32 slots (padding included) / true count
//  - cy uses X_OFFSET (upstream bug, replicated)
//  - padded slots zeroed in the 9-channel output

#define X_VOXEL 0.16f
#define Y_VOXEL 0.16f
#define X_OFFSET 0.08f   // voxel/2 + range0; used for BOTH x and y (ref bug)
#define MAX_PTS 32

__global__ __launch_bounds__(256) void pfn_kernel(
    const float4* __restrict__ pillars,   // (P, 32) as float4 per point
    const int*    __restrict__ coors,     // (P, 4)
    const int*    __restrict__ npoints,   // (P,)
    float*        __restrict__ out_coors, // (P, 4) as float (value-converted)
    float*        __restrict__ out_feat,  // (P, 9, 32)
    int P)
{
    int lane = threadIdx.x & 31;
    int hw0  = (blockIdx.x * blockDim.x + threadIdx.x) >> 5;  // half-wave id
    int nhw  = (gridDim.x * blockDim.x) >> 5;

    for (int pillar = hw0; pillar < P; pillar += nhw) {
        // Coalesced 16B/lane load: 512B contiguous per half-wave.
        float4 pt = pillars[(size_t)pillar * MAX_PTS + lane];

        // Sum xyz over ALL 32 slots (reference sums padded slots too).
        float sx = pt.x, sy = pt.y, sz = pt.z;
        #pragma unroll
        for (int off = 16; off > 0; off >>= 1) {
            sx += __shfl_xor(sx, off, 32);
            sy += __shfl_xor(sy, off, 32);
            sz += __shfl_xor(sz, off, 32);
        }

        int np = npoints[pillar];              // broadcast via cache
        float n  = (float)np;
        float mx = sx / n, my = sy / n, mz = sz / n;   // IEEE div, matches jnp

        // coors[pillar][0..3]: one coalesced 4B read per lane group of 4.
        int cv = coors[pillar * 4 + (lane & 3)];
        float cx = (float)__shfl(cv, 1, 32) * X_VOXEL + X_OFFSET;
        float cy = (float)__shfl(cv, 2, 32) * Y_VOXEL + X_OFFSET;  // ref bug: X_OFFSET

        float m  = (lane < np) ? 1.0f : 0.0f;  // zero padded slots

        float f0 = (pt.x - cx) * m;   // off_x
        float f1 = (pt.y - cy) * m;   // off_y

        // (P, 9, N) channel-major: each store = one aligned 128B line per half-wave.
        float* o = out_feat + (size_t)pillar * 9 * MAX_PTS;
        o[  0 + lane] = f0;
        o[ 32 + lane] = f1;
        o[ 64 + lane] = pt.z * m;
        o[ 96 + lane] = pt.w * m;
        o[128 + lane] = (pt.x - mx) * m;
        o[160 + lane] = (pt.y - my) * m;
        o[192 + lane] = (pt.z - mz) * m;
        o[224 + lane] = f0;
        o[256 + lane] = f1;

        // coors pass-through (int -> float value conversion; 0..400 exact).
        if (lane < 4) out_coors[pillar * 4 + lane] = (float)cv;
    }
}

extern "C" void kernel_launch(void* const* d_in, const int* in_sizes, int n_in,
                              void* d_out, int out_size, void* d_ws, size_t ws_size,
                              hipStream_t stream) {
    const float* pillars = (const float*)d_in[0];
    const int*   coors   = (const int*)d_in[1];
    const int*   npoints = (const int*)d_in[2];
    int P = in_sizes[2];                       // 200000

    float* out       = (float*)d_out;
    float* out_coors = out;                    // first P*4 elements
    float* out_feat  = out + (size_t)P * 4;    // then P*9*32

    const int threads = 256;                   // 8 pillars / block
    const int ppb = threads / 32;
    int grid = (P + ppb - 1) / ppb;
    // Guideline 11 (memory-bound): cap grid at 256 CU x 8 blocks/CU and
    // grid-stride the rest — amortizes setup, keeps scheduler fed.
    if (grid > 2048) grid = 2048;
    pfn_kernel<<<grid, threads, 0, stream>>>(
        (const float4*)pillars, coors, npoints, out_coors, out_feat, P);
}

// Round 6
// 309.285 us; speedup vs baseline: 1.0052x; 1.0052x over previous
//
#include <hip/hip_runtime.h>

// PFNLayer feature augmentation (PointPillars), MI355X.
// One 32-lane half-wave per pillar; lane = point slot. No grid-stride loop:
// R4 A/B test showed capped-grid+loop version at ~100-130us (est.) vs 54us
// traffic floor; this round reverts to one-shot max-TLP mapping.
// Layout: d_out = [coors_as_float (P*4)] ++ [features (P*9*32)].
//
// Reference semantics replicated exactly:
//  - mean = sum over ALL 32 slots (padding included) / true count
//  - cy uses X_OFFSET (upstream bug, replicated)
//  - padded slots zeroed in the 9-channel output

#define X_VOXEL 0.16f
#define Y_VOXEL 0.16f
#define X_OFFSET 0.08f   // voxel/2 + range0; used for BOTH x and y (ref bug)
#define MAX_PTS 32

__global__ __launch_bounds__(256) void pfn_kernel(
    const float4* __restrict__ pillars,   // (P, 32) as float4 per point
    const int*    __restrict__ coors,     // (P, 4)
    const int*    __restrict__ npoints,   // (P,)
    float*        __restrict__ out_coors, // (P, 4) as float (value-converted)
    float*        __restrict__ out_feat,  // (P, 9, 32)
    int P)
{
    int tid    = blockIdx.x * blockDim.x + threadIdx.x;
    int pillar = tid >> 5;          // 32 lanes per pillar
    int lane   = tid & 31;
    if (pillar >= P) return;

    // Coalesced 16B/lane load: 512B contiguous per half-wave.
    float4 pt = pillars[(size_t)pillar * MAX_PTS + lane];

    // Sum xyz over ALL 32 slots (reference sums padded slots too).
    float sx = pt.x, sy = pt.y, sz = pt.z;
    #pragma unroll
    for (int off = 16; off > 0; off >>= 1) {
        sx += __shfl_xor(sx, off, 32);
        sy += __shfl_xor(sy, off, 32);
        sz += __shfl_xor(sz, off, 32);
    }

    int np = npoints[pillar];              // broadcast via cache
    float n  = (float)np;
    float mx = sx / n, my = sy / n, mz = sz / n;   // IEEE div, matches jnp

    // coors[pillar][0..3]: one 16B segment per half-wave, then lane-broadcast.
    int cv = coors[pillar * 4 + (lane & 3)];
    float cx = (float)__shfl(cv, 1, 32) * X_VOXEL + X_OFFSET;
    float cy = (float)__shfl(cv, 2, 32) * Y_VOXEL + X_OFFSET;  // ref bug: X_OFFSET

    float m  = (lane < np) ? 1.0f : 0.0f;  // zero padded slots

    float f0 = (pt.x - cx) * m;   // off_x
    float f1 = (pt.y - cy) * m;   // off_y

    // (P, 9, N) channel-major: each store = one aligned 128B line per half-wave.
    float* o = out_feat + (size_t)pillar * 9 * MAX_PTS;
    o[  0 + lane] = f0;
    o[ 32 + lane] = f1;
    o[ 64 + lane] = pt.z * m;
    o[ 96 + lane] = pt.w * m;
    o[128 + lane] = (pt.x - mx) * m;
    o[160 + lane] = (pt.y - my) * m;
    o[192 + lane] = (pt.z - mz) * m;
    o[224 + lane] = f0;
    o[256 + lane] = f1;

    // coors pass-through (int -> float value conversion; 0..400 exact).
    if (lane < 4) out_coors[pillar * 4 + lane] = (float)cv;
}

extern "C" void kernel_launch(void* const* d_in, const int* in_sizes, int n_in,
                              void* d_out, int out_size, void* d_ws, size_t ws_size,
                              hipStream_t stream) {
    const float* pillars = (const float*)d_in[0];
    const int*   coors   = (const int*)d_in[1];
    const int*   npoints = (const int*)d_in[2];
    int P = in_sizes[2];                       // 200000

    float* out       = (float*)d_out;
    float* out_coors = out;                    // first P*4 elements
    float* out_feat  = out + (size_t)P * 4;    // then P*9*32

    const int threads = 256;                   // 8 pillars / block
    const int ppb = threads / 32;
    int grid = (P + ppb - 1) / ppb;            // 25000 blocks, one-shot
    pfn_kernel<<<grid, threads, 0, stream>>>(
        (const float4*)pillars, coors, npoints, out_coors, out_feat, P);
}

// Round 7
// 301.956 us; speedup vs baseline: 1.0296x; 1.0243x over previous
//
#include <hip/hip_runtime.h>

// PFNLayer feature augmentation (PointPillars), MI355X.
// R6 A/B: grid-stride vs one-shot identical (310.9 vs 309.3us) -> mapping
// doesn't matter; kernel est. ~90us vs 54us traffic floor. This round: make
// the store stream wide+linear (LDS-stage 8 pillars/block, write one
// contiguous float4 stream) to match the 6.4 TB/s fill-kernel pattern.
// Layout: d_out = [coors_as_float (P*4)] ++ [features (P*9*32)].
//
// Reference semantics replicated exactly:
//  - mean = sum over ALL 32 slots (padding included) / true count
//  - cy uses X_OFFSET (upstream bug, replicated)
//  - padded slots zeroed in the 9-channel output

#define X_VOXEL 0.16f
#define Y_VOXEL 0.16f
#define X_OFFSET 0.08f   // voxel/2 + range0; used for BOTH x and y (ref bug)
#define MAX_PTS 32
#define PPB 8            // pillars per 256-thread block

__global__ __launch_bounds__(256) void pfn_kernel(
    const float4* __restrict__ pillars,   // (P, 32) as float4 per point
    const int*    __restrict__ coors,     // (P, 4)
    const int*    __restrict__ npoints,   // (P,)
    float*        __restrict__ out_coors, // (P, 4) as float (value-converted)
    float*        __restrict__ out_feat,  // (P, 9, 32)
    int P)
{
    __shared__ float lds[PPB * 9 * MAX_PTS];   // 9216 B per block

    int tid  = threadIdx.x;
    int lane = tid & 31;
    int hw   = tid >> 5;                  // half-wave id in block = local pillar
    int base = blockIdx.x * PPB;
    int pillar = base + hw;

    if (pillar < P) {
        // Coalesced 16B/lane load: 512B contiguous per half-wave.
        float4 pt = pillars[(size_t)pillar * MAX_PTS + lane];

        // Sum xyz over ALL 32 slots (reference sums padded slots too).
        float sx = pt.x, sy = pt.y, sz = pt.z;
        #pragma unroll
        for (int off = 16; off > 0; off >>= 1) {
            sx += __shfl_xor(sx, off, 32);
            sy += __shfl_xor(sy, off, 32);
            sz += __shfl_xor(sz, off, 32);
        }

        int np = npoints[pillar];
        float n  = (float)np;
        float mx = sx / n, my = sy / n, mz = sz / n;   // IEEE div, matches jnp

        int cv = coors[pillar * 4 + (lane & 3)];
        float cx = (float)__shfl(cv, 1, 32) * X_VOXEL + X_OFFSET;
        float cy = (float)__shfl(cv, 2, 32) * Y_VOXEL + X_OFFSET;  // ref bug

        float m  = (lane < np) ? 1.0f : 0.0f;  // zero padded slots
        float f0 = (pt.x - cx) * m;   // off_x
        float f1 = (pt.y - cy) * m;   // off_y

        // Stage [pillar][channel][lane]; half-wave pair aliases banks 2-way
        // (free per m136).
        float* l = lds + hw * 288 + lane;
        l[  0] = f0;
        l[ 32] = f1;
        l[ 64] = pt.z * m;
        l[ 96] = pt.w * m;
        l[128] = (pt.x - mx) * m;
        l[160] = (pt.y - my) * m;
        l[192] = (pt.z - mz) * m;
        l[224] = f0;
        l[256] = f1;
    }
    __syncthreads();

    // Linear float4 write-out of the block's pillars: 9216B contiguous,
    // dwordx4 per lane — same stream shape as the 6.4 TB/s fill kernel.
    int npil = P - base; if (npil > PPB) npil = PPB;
    int nf4  = npil * 72;                       // 72 float4 per pillar
    float4* dst = (float4*)(out_feat + (size_t)base * 288);
    const float4* src = (const float4*)lds;
    for (int i = tid; i < nf4; i += 256)
        dst[i] = src[i];

    // coors pass-through: one float4 per pillar -> one aligned 128B line
    // per block (replaces 16B partial-line stores).
    if (tid < npil) {
        int4 c4 = ((const int4*)coors)[base + tid];
        ((float4*)out_coors)[base + tid] =
            make_float4((float)c4.x, (float)c4.y, (float)c4.z, (float)c4.w);
    }
}

extern "C" void kernel_launch(void* const* d_in, const int* in_sizes, int n_in,
                              void* d_out, int out_size, void* d_ws, size_t ws_size,
                              hipStream_t stream) {
    const float* pillars = (const float*)d_in[0];
    const int*   coors   = (const int*)d_in[1];
    const int*   npoints = (const int*)d_in[2];
    int P = in_sizes[2];                       // 200000

    float* out       = (float*)d_out;
    float* out_coors = out;                    // first P*4 elements
    float* out_feat  = out + (size_t)P * 4;    // then P*9*32

    const int threads = 256;                   // 8 pillars / block
    int grid = (P + PPB - 1) / PPB;            // 25000 blocks
    pfn_kernel<<<grid, threads, 0, stream>>>(
        (const float4*)pillars, coors, npoints, out_coors, out_feat, P);
}